// Round 7
// baseline (811.446 us; speedup 1.0000x reference)
//
#include <hip/hip_runtime.h>

#define N_ENT 50000
#define N_REL 500
#define N_EDGE 500000
#define HEADS 2
#define DIM 64
#define POW_ITER 3
#define ALPHA 0.15f
#define LN_EPS 1e-5f
#define KBUK 4
#define DSTBLK 12500           // N_ENT / KBUK
#define M2 (N_ENT * KBUK)      // 200000 segmented-rowptr entries
#define NBLK2 196              // ceil(M2/1024)

typedef unsigned uv4 __attribute__((ext_vector_type(4)));
typedef float fv4 __attribute__((ext_vector_type(4)));

// bf16 round-to-nearest-even pack
static __device__ __forceinline__ unsigned bf16_rne(float f) {
  unsigned u = __float_as_uint(f);
  return (u + 0x7FFFu + ((u >> 16) & 1u)) >> 16;
}

// ================= CSR build (dst-bucketed; once per launch) =================
__global__ void deg2_kernel(const int* __restrict__ src, const int* __restrict__ dst,
                            int* __restrict__ deg2) {
  int e = blockIdx.x * blockDim.x + threadIdx.x;
  if (e >= N_EDGE) return;
  int k = dst[e] / DSTBLK;
  atomicAdd(&deg2[src[e] * KBUK + k], 1);
}

// Phase 1: per-block (1024) exclusive scan over M elements
__global__ __launch_bounds__(1024) void scan1_kernel(const int* __restrict__ deg,
                                                     int* __restrict__ exc,
                                                     int* __restrict__ bsum, int M) {
  __shared__ int tmp[1024];
  int tid = threadIdx.x;
  int i = blockIdx.x * 1024 + tid;
  int v = (i < M) ? deg[i] : 0;
  tmp[tid] = v;
  __syncthreads();
  for (int off = 1; off < 1024; off <<= 1) {
    int t = (tid >= off) ? tmp[tid - off] : 0;
    __syncthreads();
    tmp[tid] += t;
    __syncthreads();
  }
  if (i < M) exc[i] = tmp[tid] - v;
  if (tid == 1023) bsum[blockIdx.x] = tmp[1023];
}

// Phase 2: one block (256 threads) scans up to 256 block sums
__global__ __launch_bounds__(256) void scan2_kernel(const int* __restrict__ bsum,
                                                    int* __restrict__ boff, int nb) {
  __shared__ int tmp[256];
  int t = threadIdx.x;
  int v = (t < nb) ? bsum[t] : 0;
  tmp[t] = v;
  __syncthreads();
  for (int off = 1; off < 256; off <<= 1) {
    int u = (t >= off) ? tmp[t - off] : 0;
    __syncthreads();
    tmp[t] += u;
    __syncthreads();
  }
  if (t < nb) boff[t] = tmp[t] - v;
  if (t == nb - 1) boff[nb] = tmp[t];
}

// Phase 3: add block offsets -> rowptr2
__global__ __launch_bounds__(1024) void scan3_kernel(const int* __restrict__ exc,
                                                     const int* __restrict__ boff,
                                                     int* __restrict__ rowptr, int M) {
  int i = blockIdx.x * 1024 + threadIdx.x;
  if (i < M) rowptr[i] = exc[i] + boff[i >> 10];
  if (i == M) rowptr[M] = boff[(M + 1023) >> 10];
}

// scatter into bucketed CSR: csr_dst[p], csr_et[p]
__global__ void scatter_kernel(const int* __restrict__ src, const int* __restrict__ dst,
                               const int* __restrict__ et, int* __restrict__ cursor,
                               int* __restrict__ csr_dst, int* __restrict__ csr_et) {
  int e = blockIdx.x * blockDim.x + threadIdx.x;
  if (e >= N_EDGE) return;
  int d = dst[e];
  int k = d / DSTBLK;
  int p = atomicAdd(&cursor[src[e] * KBUK + k], 1);
  csr_dst[p] = d;
  csr_et[p] = et[e];
}

// ================= LayerNorm: one wave per node =================
__global__ void ln_kernel(const float* __restrict__ x, const float* __restrict__ g,
                          const float* __restrict__ b, float* __restrict__ h) {
  int wid = (blockIdx.x * blockDim.x + threadIdx.x) >> 6;
  int lane = threadIdx.x & 63;
  if (wid >= N_ENT) return;
  float v = x[wid * 64 + lane];
  float s = v;
#pragma unroll
  for (int off = 32; off; off >>= 1) s += __shfl_xor(s, off);
  float mu = s * (1.0f / 64.0f);
  float d = v - mu;
  float s2 = d * d;
#pragma unroll
  for (int off = 32; off; off >>= 1) s2 += __shfl_xor(s2, off);
  float rs = rsqrtf(s2 * (1.0f / 64.0f) + LN_EPS);
  h[wid * 64 + lane] = d * rs * g[lane] + b[lane];
}

// ================= node scores: W column in VGPRs, x row via scalar loads =================
__global__ __launch_bounds__(256) void scores_w_kernel(
    const float* __restrict__ x, const float* __restrict__ W,
    const float* __restrict__ att, float* __restrict__ s_out, int M) {
  int lane = threadIdx.x & 63;
  float w0[64], w1[64];
#pragma unroll
  for (int k = 0; k < 64; ++k) {
    w0[k] = W[k * 128 + lane];
    w1[k] = W[k * 128 + lane + 64];
  }
  float a0v = att[lane], a1v = att[lane + 64];
  int gw = (blockIdx.x * 256 + threadIdx.x) >> 6;
  int nw = (gridDim.x * 256) >> 6;
  for (int n = gw; n < M; n += nw) {
    int nu = __builtin_amdgcn_readfirstlane(n);
    const float* xr = x + nu * 64;
    float p0 = 0.f, p1 = 0.f, p2 = 0.f, p3 = 0.f;
#pragma unroll
    for (int k = 0; k < 32; ++k) {
      float xa = xr[k], xb = xr[k + 32];
      p0 += xa * w0[k];
      p1 += xb * w0[k + 32];
      p2 += xa * w1[k];
      p3 += xb * w1[k + 32];
    }
    float t0 = tanhf(p0 + p1) * a0v;
    float t1 = tanhf(p2 + p3) * a1v;
#pragma unroll
    for (int off = 32; off; off >>= 1) {
      t0 += __shfl_xor(t0, off);
      t1 += __shfl_xor(t1, off);
    }
    if (lane == 0) ((float2*)s_out)[nu] = make_float2(t0, t1);
  }
}

// ================= edge pass in CSR order: one thread per node =================
// coalesced csr_w writes, register z accumulation, no atomics. cinv = (1-a)/z.
__global__ __launch_bounds__(256) void edge_csr_kernel(
    const int* __restrict__ rowptr2, const int* __restrict__ csr_dst,
    const int* __restrict__ csr_et, const float* __restrict__ s_h,
    const float* __restrict__ s_t, const float* __restrict__ s_r,
    float* __restrict__ csr_w, float* __restrict__ cinv) {
  int n = blockIdx.x * blockDim.x + threadIdx.x;
  if (n >= N_ENT) return;
  int p0 = rowptr2[n * KBUK], p1 = rowptr2[n * KBUK + KBUK];
  float2 sh = ((const float2*)s_h)[n];
  float z0 = 0.f, z1 = 0.f;
  for (int p = p0; p < p1; ++p) {
    int d = csr_dst[p];
    int r = csr_et[p];
    float2 st = ((const float2*)s_t)[d];
    float2 sr = ((const float2*)s_r)[r];
    float sc0 = sh.x + st.x + sr.x;
    float sc1 = sh.y + st.y + sr.y;
    sc0 = (sc0 >= 0.f) ? sc0 : 0.01f * sc0;
    sc1 = (sc1 >= 0.f) ? sc1 : 0.01f * sc1;
    float w0 = expf(sc0), w1 = expf(sc1);
    ((float2*)csr_w)[p] = make_float2(w0, w1);
    z0 += w0;
    z1 += w1;
  }
  float c0 = (p1 > p0) ? (1.0f - ALPHA) / z0 : 0.f;
  float c1 = (p1 > p0) ? (1.0f - ALPHA) / z1 : 0.f;
  ((float2*)cinv)[n] = make_float2(c0, c1);
}

// ================= bucketed CSR SpMM: pass k gathers only Z[k*12500 .. ) =================
// 16 lanes per node (8 dims each), 4 nodes per wave, no cross-lane reduce.
// IN_H: gather f32 h (64-dim, head-bcast) else bf16 Z (128-dim).
// FINAL: accumulate in f32 Zf (feeds out_kernel) else bf16 Zacc (next iter's gather src).
template <int IN_H, int FINAL>
__global__ __launch_bounds__(256) void spmmb_kernel(
    const int* __restrict__ rowptr2, const int* __restrict__ csr_dst,
    const float* __restrict__ csr_w, const float* __restrict__ cinv,
    const float* __restrict__ h, const void* __restrict__ Zin_,
    void* __restrict__ Zout_, int k) {
  const unsigned short* Zin_b = (const unsigned short*)Zin_;
  int lane = threadIdx.x & 63;
  int g = lane >> 4;           // node sub-index within wave
  int l16 = lane & 15;         // dims 8*l16 .. 8*l16+7
  int hh = l16 >> 3;
  int hoff = 8 * (l16 & 7);    // offset within 64-dim head row
  int wave = (blockIdx.x * 256 + threadIdx.x) >> 6;
  int nwaves = (gridDim.x * 256) >> 6;
  for (int wb = wave; wb < N_ENT / 4; wb += nwaves) {
    int n = wb * 4 + g;
    int p0 = rowptr2[n * KBUK + k], p1 = rowptr2[n * KBUK + k + 1];
    float acc[8];
#pragma unroll
    for (int j = 0; j < 8; ++j) acc[j] = 0.f;
    for (int p = p0; p < p1; ++p) {
      int d = csr_dst[p];
      float2 w2 = ((const float2*)csr_w)[p];
      float a = hh ? w2.y : w2.x;
      float f[8];
      if (IN_H) {
        const float* zp = h + d * 64 + hoff;
        float4 z0 = *(const float4*)zp;
        float4 z1 = *(const float4*)(zp + 4);
        f[0] = z0.x; f[1] = z0.y; f[2] = z0.z; f[3] = z0.w;
        f[4] = z1.x; f[5] = z1.y; f[6] = z1.z; f[7] = z1.w;
      } else {
        uv4 q = *(const uv4*)(Zin_b + d * 128 + 8 * l16);
        f[0] = __uint_as_float(q.x << 16); f[1] = __uint_as_float(q.x & 0xFFFF0000u);
        f[2] = __uint_as_float(q.y << 16); f[3] = __uint_as_float(q.y & 0xFFFF0000u);
        f[4] = __uint_as_float(q.z << 16); f[5] = __uint_as_float(q.z & 0xFFFF0000u);
        f[6] = __uint_as_float(q.w << 16); f[7] = __uint_as_float(q.w & 0xFFFF0000u);
      }
#pragma unroll
      for (int j = 0; j < 8; ++j) acc[j] += a * f[j];
    }
    float c = cinv[n * 2 + hh];
    float o[8];
    if (k == 0) {
      const float* hp = h + n * 64 + hoff;
#pragma unroll
      for (int j = 0; j < 8; ++j) o[j] = ALPHA * hp[j] + c * acc[j];
    } else if (FINAL) {
      const float* bp = (const float*)Zout_ + n * 128 + 8 * l16;
      fv4 b0 = __builtin_nontemporal_load((const fv4*)bp);
      fv4 b1 = __builtin_nontemporal_load((const fv4*)(bp + 4));
      o[0] = b0.x + c * acc[0]; o[1] = b0.y + c * acc[1];
      o[2] = b0.z + c * acc[2]; o[3] = b0.w + c * acc[3];
      o[4] = b1.x + c * acc[4]; o[5] = b1.y + c * acc[5];
      o[6] = b1.z + c * acc[6]; o[7] = b1.w + c * acc[7];
    } else {
      const unsigned short* bp = (const unsigned short*)Zout_ + n * 128 + 8 * l16;
      uv4 q = __builtin_nontemporal_load((const uv4*)bp);
      o[0] = __uint_as_float(q.x << 16) + c * acc[0];
      o[1] = __uint_as_float(q.x & 0xFFFF0000u) + c * acc[1];
      o[2] = __uint_as_float(q.y << 16) + c * acc[2];
      o[3] = __uint_as_float(q.y & 0xFFFF0000u) + c * acc[3];
      o[4] = __uint_as_float(q.z << 16) + c * acc[4];
      o[5] = __uint_as_float(q.z & 0xFFFF0000u) + c * acc[5];
      o[6] = __uint_as_float(q.w << 16) + c * acc[6];
      o[7] = __uint_as_float(q.w & 0xFFFF0000u) + c * acc[7];
    }
    if (FINAL) {
      float* op = (float*)Zout_ + n * 128 + 8 * l16;
      fv4 s0, s1;
      s0.x = o[0]; s0.y = o[1]; s0.z = o[2]; s0.w = o[3];
      s1.x = o[4]; s1.y = o[5]; s1.z = o[6]; s1.w = o[7];
      __builtin_nontemporal_store(s0, (fv4*)op);
      __builtin_nontemporal_store(s1, (fv4*)(op + 4));
    } else {
      unsigned short* ob = (unsigned short*)Zout_ + n * 128 + 8 * l16;
      uv4 qo;
      qo.x = bf16_rne(o[0]) | (bf16_rne(o[1]) << 16);
      qo.y = bf16_rne(o[2]) | (bf16_rne(o[3]) << 16);
      qo.z = bf16_rne(o[4]) | (bf16_rne(o[5]) << 16);
      qo.w = bf16_rne(o[6]) | (bf16_rne(o[7]) << 16);
      __builtin_nontemporal_store(qo, (uv4*)ob);
    }
  }
}

// ================= output: lane = column j; W_o column in 128 VGPRs; Z row via s_load =================
__global__ __launch_bounds__(256) void out_kernel(
    const float* __restrict__ Z, const float* __restrict__ Wo,
    const float* __restrict__ x, float* __restrict__ out) {
  int lane = threadIdx.x & 63;
  float wo[128];
#pragma unroll
  for (int c = 0; c < 128; ++c) wo[c] = Wo[c * 64 + lane];
  int gw = (blockIdx.x * 256 + threadIdx.x) >> 6;
  int nw = (gridDim.x * 256) >> 6;
  for (int n = gw; n < N_ENT; n += nw) {
    int nu = __builtin_amdgcn_readfirstlane(n);
    const float* zr = Z + nu * 128;
    float a0 = 0.f, a1 = 0.f, a2 = 0.f, a3 = 0.f;
#pragma unroll
    for (int c = 0; c < 32; ++c) {
      a0 += zr[c] * wo[c];
      a1 += zr[c + 32] * wo[c + 32];
      a2 += zr[c + 64] * wo[c + 64];
      a3 += zr[c + 96] * wo[c + 96];
    }
    out[nu * 64 + lane] = (a0 + a1) + (a2 + a3) + x[nu * 64 + lane];
  }
}

extern "C" void kernel_launch(void* const* d_in, const int* in_sizes, int n_in,
                              void* d_out, int out_size, void* d_ws, size_t ws_size,
                              hipStream_t stream) {
  const float* ent0 = (const float*)d_in[0];
  const float* rel  = (const float*)d_in[1];
  const int* eidx   = (const int*)d_in[2];
  const int* src    = eidx;
  const int* dst    = eidx + N_EDGE;
  const int* et     = (const int*)d_in[3];
  const float* gam  = (const float*)d_in[4];
  const float* bet  = (const float*)d_in[5];
  const float* W_h  = (const float*)d_in[6];
  const float* W_t  = (const float*)d_in[7];
  const float* W_r  = (const float*)d_in[8];
  const float* att_h = (const float*)d_in[9];
  const float* att_t = (const float*)d_in[10];
  const float* att_r = (const float*)d_in[11];
  const float* W_o  = (const float*)d_in[12];
  float* outp = (float*)d_out;

  char* w = (char*)d_ws;
  auto alloc = [&](size_t bytes) {
    char* p = w;
    w += (bytes + 255) & ~(size_t)255;
    return p;
  };
  float* ent1   = (float*)alloc((size_t)N_ENT * 64 * 4);
  float* h      = (float*)alloc((size_t)N_ENT * 64 * 4);
  float* s_h    = (float*)alloc((size_t)N_ENT * 2 * 4);
  float* s_t    = (float*)alloc((size_t)N_ENT * 2 * 4);
  float* s_r    = (float*)alloc((size_t)N_REL * 2 * 4);
  float* cinv   = (float*)alloc((size_t)N_ENT * 2 * 4);
  float* csr_w  = (float*)alloc((size_t)N_EDGE * 2 * 4);
  unsigned short* Zb0 = (unsigned short*)alloc((size_t)N_ENT * 128 * 2);
  unsigned short* Zb1 = (unsigned short*)alloc((size_t)N_ENT * 128 * 2);
  float* Zf     = (float*)alloc((size_t)N_ENT * 128 * 4);
  int* deg2     = (int*)alloc((size_t)M2 * 4);
  int* exc      = (int*)alloc((size_t)M2 * 4);
  int* bsum     = (int*)alloc((size_t)NBLK2 * 4);
  int* boff     = (int*)alloc((size_t)(NBLK2 + 1) * 4);
  int* rowptr2  = (int*)alloc((size_t)(M2 + 1) * 4);
  int* cursor   = (int*)alloc((size_t)M2 * 4);
  int* csr_dst  = (int*)alloc((size_t)N_EDGE * 4);
  int* csr_et   = (int*)alloc((size_t)N_EDGE * 4);

  const int EB = (N_EDGE + 255) / 256;

  // ---- bucketed CSR build ----
  hipMemsetAsync(deg2, 0, (size_t)M2 * 4, stream);
  deg2_kernel<<<EB, 256, 0, stream>>>(src, dst, deg2);
  scan1_kernel<<<NBLK2, 1024, 0, stream>>>(deg2, exc, bsum, M2);
  scan2_kernel<<<1, 256, 0, stream>>>(bsum, boff, NBLK2);
  scan3_kernel<<<NBLK2, 1024, 0, stream>>>(exc, boff, rowptr2, M2);
  hipMemcpyAsync(cursor, rowptr2, (size_t)M2 * 4, hipMemcpyDeviceToDevice, stream);
  scatter_kernel<<<EB, 256, 0, stream>>>(src, dst, et, cursor, csr_dst, csr_et);

  for (int l = 0; l < 2; ++l) {
    const float* x = (l == 0) ? ent0 : ent1;
    float* y = (l == 0) ? ent1 : outp;

    ln_kernel<<<(N_ENT + 3) / 4, 256, 0, stream>>>(x, gam + l * 64, bet + l * 64, h);
    scores_w_kernel<<<1024, 256, 0, stream>>>(h, W_h + l * 8192, att_h + l * 128, s_h, N_ENT);
    scores_w_kernel<<<1024, 256, 0, stream>>>(h, W_t + l * 8192, att_t + l * 128, s_t, N_ENT);
    scores_w_kernel<<<8, 256, 0, stream>>>(rel, W_r + l * 8192, att_r + l * 128, s_r, N_REL);

    edge_csr_kernel<<<(N_ENT + 255) / 256, 256, 0, stream>>>(
        rowptr2, csr_dst, csr_et, s_h, s_t, s_r, csr_w, cinv);

    // ---- PPR power iteration: each iter = 4 dst-bucketed passes ----
    for (int k = 0; k < KBUK; ++k)
      spmmb_kernel<1, 0><<<2048, 256, 0, stream>>>(rowptr2, csr_dst, csr_w, cinv, h, h, Zb0, k);
    for (int k = 0; k < KBUK; ++k)
      spmmb_kernel<0, 0><<<2048, 256, 0, stream>>>(rowptr2, csr_dst, csr_w, cinv, h, Zb0, Zb1, k);
    for (int k = 0; k < KBUK; ++k)
      spmmb_kernel<0, 1><<<2048, 256, 0, stream>>>(rowptr2, csr_dst, csr_w, cinv, h, Zb1, Zf, k);

    out_kernel<<<512, 256, 0, stream>>>(Zf, W_o + l * 8192, x, y);
  }
}

// Round 9
// 511.146 us; speedup vs baseline: 1.5875x; 1.5875x over previous
//
#include <hip/hip_runtime.h>

#define N_ENT 50000
#define N_REL 500
#define N_EDGE 500000
#define HEADS 2
#define DIM 64
#define POW_ITER 3
#define ALPHA 0.15f
#define LN_EPS 1e-5f
#define NBLK 49  // ceil(N_ENT/1024)

typedef unsigned uv4 __attribute__((ext_vector_type(4)));
typedef float fv4 __attribute__((ext_vector_type(4)));

// bf16 round-to-nearest-even pack
static __device__ __forceinline__ unsigned bf16_rne(float f) {
  unsigned u = __float_as_uint(f);
  return (u + 0x7FFFu + ((u >> 16) & 1u)) >> 16;
}

// ================= CSR build (once per launch; graph is layer-invariant) =================
__global__ void deg_kernel(const int* __restrict__ src, int* __restrict__ deg) {
  int e = blockIdx.x * blockDim.x + threadIdx.x;
  if (e >= N_EDGE) return;
  atomicAdd(&deg[src[e]], 1);
}

__global__ __launch_bounds__(1024) void scan1_kernel(const int* __restrict__ deg,
                                                     int* __restrict__ exc,
                                                     int* __restrict__ bsum) {
  __shared__ int tmp[1024];
  int tid = threadIdx.x;
  int i = blockIdx.x * 1024 + tid;
  int v = (i < N_ENT) ? deg[i] : 0;
  tmp[tid] = v;
  __syncthreads();
  for (int off = 1; off < 1024; off <<= 1) {
    int t = (tid >= off) ? tmp[tid - off] : 0;
    __syncthreads();
    tmp[tid] += t;
    __syncthreads();
  }
  if (i < N_ENT) exc[i] = tmp[tid] - v;
  if (tid == 1023) bsum[blockIdx.x] = tmp[1023];
}

__global__ void scan2_kernel(const int* __restrict__ bsum, int* __restrict__ boff) {
  int t = threadIdx.x;  // 64 threads
  int v = (t < NBLK) ? bsum[t] : 0;
  int incl = v;
#pragma unroll
  for (int off = 1; off < 64; off <<= 1) {
    int u = __shfl_up(incl, off);
    if (t >= off) incl += u;
  }
  if (t < NBLK) boff[t] = incl - v;
  if (t == NBLK - 1) boff[NBLK] = incl;
}

__global__ __launch_bounds__(1024) void scan3_kernel(const int* __restrict__ exc,
                                                     const int* __restrict__ boff,
                                                     int* __restrict__ rowptr) {
  int i = blockIdx.x * 1024 + threadIdx.x;
  if (i < N_ENT) rowptr[i] = exc[i] + boff[i >> 10];
  if (i == N_ENT) rowptr[N_ENT] = boff[NBLK];
}

// scatter: csr_dst[p] = dst[e]; csr_et[p] = et[e]
__global__ void scatter_kernel(const int* __restrict__ src, const int* __restrict__ dst,
                               const int* __restrict__ et, int* __restrict__ cursor,
                               int* __restrict__ csr_dst, int* __restrict__ csr_et) {
  int e = blockIdx.x * blockDim.x + threadIdx.x;
  if (e >= N_EDGE) return;
  int p = atomicAdd(&cursor[src[e]], 1);
  csr_dst[p] = dst[e];
  csr_et[p] = et[e];
}

// ================= LayerNorm: one wave per node; writes f32 h and bf16 h_bf =================
__global__ void ln_kernel(const float* __restrict__ x, const float* __restrict__ g,
                          const float* __restrict__ b, float* __restrict__ h,
                          unsigned short* __restrict__ h_bf) {
  int wid = (blockIdx.x * blockDim.x + threadIdx.x) >> 6;
  int lane = threadIdx.x & 63;
  if (wid >= N_ENT) return;
  float v = x[wid * 64 + lane];
  float s = v;
#pragma unroll
  for (int off = 32; off; off >>= 1) s += __shfl_xor(s, off);
  float mu = s * (1.0f / 64.0f);
  float d = v - mu;
  float s2 = d * d;
#pragma unroll
  for (int off = 32; off; off >>= 1) s2 += __shfl_xor(s2, off);
  float rs = rsqrtf(s2 * (1.0f / 64.0f) + LN_EPS);
  float hv = d * rs * g[lane] + b[lane];
  h[wid * 64 + lane] = hv;
  h_bf[wid * 64 + lane] = (unsigned short)bf16_rne(hv);
}

// ================= node scores: W column in VGPRs, x row via scalar loads =================
__global__ __launch_bounds__(256) void scores_w_kernel(
    const float* __restrict__ x, const float* __restrict__ W,
    const float* __restrict__ att, float* __restrict__ s_out, int M) {
  int lane = threadIdx.x & 63;
  float w0[64], w1[64];
#pragma unroll
  for (int k = 0; k < 64; ++k) {
    w0[k] = W[k * 128 + lane];
    w1[k] = W[k * 128 + lane + 64];
  }
  float a0v = att[lane], a1v = att[lane + 64];
  int gw = (blockIdx.x * 256 + threadIdx.x) >> 6;
  int nw = (gridDim.x * 256) >> 6;
  for (int n = gw; n < M; n += nw) {
    int nu = __builtin_amdgcn_readfirstlane(n);
    const float* xr = x + nu * 64;
    float p0 = 0.f, p1 = 0.f, p2 = 0.f, p3 = 0.f;
#pragma unroll
    for (int k = 0; k < 32; ++k) {
      float xa = xr[k], xb = xr[k + 32];
      p0 += xa * w0[k];
      p1 += xb * w0[k + 32];
      p2 += xa * w1[k];
      p3 += xb * w1[k + 32];
    }
    float t0 = tanhf(p0 + p1) * a0v;
    float t1 = tanhf(p2 + p3) * a1v;
#pragma unroll
    for (int off = 32; off; off >>= 1) {
      t0 += __shfl_xor(t0, off);
      t1 += __shfl_xor(t1, off);
    }
    if (lane == 0) ((float2*)s_out)[nu] = make_float2(t0, t1);
  }
}

// ================= edge pass in CSR order: one thread per node =================
__global__ __launch_bounds__(256) void edge_csr_kernel(
    const int* __restrict__ rowptr, const int* __restrict__ csr_dst,
    const int* __restrict__ csr_et, const float* __restrict__ s_h,
    const float* __restrict__ s_t, const float* __restrict__ s_r,
    float* __restrict__ csr_w, float* __restrict__ cinv) {
  int n = blockIdx.x * blockDim.x + threadIdx.x;
  if (n >= N_ENT) return;
  int p0 = rowptr[n], p1 = rowptr[n + 1];
  float2 sh = ((const float2*)s_h)[n];
  float z0 = 0.f, z1 = 0.f;
  for (int p = p0; p < p1; ++p) {
    int d = csr_dst[p];
    int r = csr_et[p];
    float2 st = ((const float2*)s_t)[d];
    float2 sr = ((const float2*)s_r)[r];
    float sc0 = sh.x + st.x + sr.x;
    float sc1 = sh.y + st.y + sr.y;
    sc0 = (sc0 >= 0.f) ? sc0 : 0.01f * sc0;
    sc1 = (sc1 >= 0.f) ? sc1 : 0.01f * sc1;
    float w0 = expf(sc0), w1 = expf(sc1);
    ((float2*)csr_w)[p] = make_float2(w0, w1);
    z0 += w0;
    z1 += w1;
  }
  float c0 = (p1 > p0) ? (1.0f - ALPHA) / z0 : 0.f;
  float c1 = (p1 > p0) ? (1.0f - ALPHA) / z1 : 0.f;
  ((float2*)cinv)[n] = make_float2(c0, c1);
}

// ================= monolithic CSR SpMM: wave per node; 4 edge slots x 8 dims/lane =================
// IN_H=1: gather bf16 h_bf rows (64-dim, head-bcast, 128B/edge). IN_H=0: gather bf16 Z (128-dim).
// Output packed bf16. Zout[n,t] = ALPHA*h[n,t&63] + cinv[n,hh] * sum_e w_e * Zin[dst_e,t]
template <int IN_H>
__global__ __launch_bounds__(256) void spmm_kernel(
    const int* __restrict__ rowptr, const int* __restrict__ csr_dst,
    const float* __restrict__ csr_w, const float* __restrict__ cinv,
    const float* __restrict__ h, const unsigned short* __restrict__ Zin_b,
    unsigned short* __restrict__ Zout_b) {
  int lane = threadIdx.x & 63;
  int slot = lane >> 4;        // 4 edge slots per wave
  int l16 = lane & 15;         // dims 8*l16 .. 8*l16+7
  int hh = l16 >> 3;           // head
  int hoff = 8 * (l16 & 7);    // offset within 64-dim head row
  int gw = (blockIdx.x * 256 + threadIdx.x) >> 6;
  int nw = (gridDim.x * 256) >> 6;
  for (int n = gw; n < N_ENT; n += nw) {
    int p0 = rowptr[n], p1 = rowptr[n + 1];
    float acc[8];
#pragma unroll
    for (int j = 0; j < 8; ++j) acc[j] = 0.f;
    for (int p = p0 + slot; p < p1; p += 4) {
      int d = csr_dst[p];
      float2 w2 = ((const float2*)csr_w)[p];
      float a = hh ? w2.y : w2.x;
      uv4 q;
      if (IN_H) {
        q = *(const uv4*)(Zin_b + d * 64 + hoff);      // 8 bf16 of 64-dim row
      } else {
        q = *(const uv4*)(Zin_b + d * 128 + 8 * l16);  // 8 bf16 of 128-dim row
      }
      acc[0] += a * __uint_as_float(q.x << 16);
      acc[1] += a * __uint_as_float(q.x & 0xFFFF0000u);
      acc[2] += a * __uint_as_float(q.y << 16);
      acc[3] += a * __uint_as_float(q.y & 0xFFFF0000u);
      acc[4] += a * __uint_as_float(q.z << 16);
      acc[5] += a * __uint_as_float(q.z & 0xFFFF0000u);
      acc[6] += a * __uint_as_float(q.w << 16);
      acc[7] += a * __uint_as_float(q.w & 0xFFFF0000u);
    }
#pragma unroll
    for (int j = 0; j < 8; ++j) {
      acc[j] += __shfl_xor(acc[j], 16);
      acc[j] += __shfl_xor(acc[j], 32);
    }
    if (slot == 0) {
      float c = cinv[n * 2 + hh];
      const float* hp = h + n * 64 + hoff;
      float o[8];
#pragma unroll
      for (int j = 0; j < 8; ++j) o[j] = ALPHA * hp[j] + c * acc[j];
      uv4 qo;
      qo.x = bf16_rne(o[0]) | (bf16_rne(o[1]) << 16);
      qo.y = bf16_rne(o[2]) | (bf16_rne(o[3]) << 16);
      qo.z = bf16_rne(o[4]) | (bf16_rne(o[5]) << 16);
      qo.w = bf16_rne(o[6]) | (bf16_rne(o[7]) << 16);
      *(uv4*)(Zout_b + n * 128 + 8 * l16) = qo;
    }
  }
}

// ================= output: lane = col j; W_o column in 128 VGPRs; bf16 Z row (128 dims = 16 uv4)
// via 16 wave-uniform vector loads (HW broadcast, pipelined) =================
__global__ __launch_bounds__(256) void out_kernel(
    const unsigned short* __restrict__ Zb, const float* __restrict__ Wo,
    const float* __restrict__ x, float* __restrict__ out) {
  int lane = threadIdx.x & 63;
  float wo[128];
#pragma unroll
  for (int c = 0; c < 128; ++c) wo[c] = Wo[c * 64 + lane];
  int gw = (blockIdx.x * 256 + threadIdx.x) >> 6;
  int nw = (gridDim.x * 256) >> 6;
  for (int n = gw; n < N_ENT; n += nw) {
    const uv4* zr = (const uv4*)(Zb + (size_t)n * 128);  // 128 bf16 = 16 uv4
    uv4 qq[16];
#pragma unroll
    for (int i = 0; i < 16; ++i) qq[i] = zr[i];
    float acc = 0.f;
#pragma unroll
    for (int i = 0; i < 16; ++i) {
      acc += __uint_as_float(qq[i].x << 16) * wo[8 * i + 0];
      acc += __uint_as_float(qq[i].x & 0xFFFF0000u) * wo[8 * i + 1];
      acc += __uint_as_float(qq[i].y << 16) * wo[8 * i + 2];
      acc += __uint_as_float(qq[i].y & 0xFFFF0000u) * wo[8 * i + 3];
      acc += __uint_as_float(qq[i].z << 16) * wo[8 * i + 4];
      acc += __uint_as_float(qq[i].z & 0xFFFF0000u) * wo[8 * i + 5];
      acc += __uint_as_float(qq[i].w << 16) * wo[8 * i + 6];
      acc += __uint_as_float(qq[i].w & 0xFFFF0000u) * wo[8 * i + 7];
    }
    out[n * 64 + lane] = acc + x[n * 64 + lane];
  }
}

extern "C" void kernel_launch(void* const* d_in, const int* in_sizes, int n_in,
                              void* d_out, int out_size, void* d_ws, size_t ws_size,
                              hipStream_t stream) {
  const float* ent0 = (const float*)d_in[0];
  const float* rel  = (const float*)d_in[1];
  const int* eidx   = (const int*)d_in[2];
  const int* src    = eidx;
  const int* dst    = eidx + N_EDGE;
  const int* et     = (const int*)d_in[3];
  const float* gam  = (const float*)d_in[4];
  const float* bet  = (const float*)d_in[5];
  const float* W_h  = (const float*)d_in[6];
  const float* W_t  = (const float*)d_in[7];
  const float* W_r  = (const float*)d_in[8];
  const float* att_h = (const float*)d_in[9];
  const float* att_t = (const float*)d_in[10];
  const float* att_r = (const float*)d_in[11];
  const float* W_o  = (const float*)d_in[12];
  float* outp = (float*)d_out;

  char* w = (char*)d_ws;
  auto alloc = [&](size_t bytes) {
    char* p = w;
    w += (bytes + 255) & ~(size_t)255;
    return p;
  };
  float* ent1   = (float*)alloc((size_t)N_ENT * 64 * 4);
  float* h      = (float*)alloc((size_t)N_ENT * 64 * 4);
  unsigned short* h_bf = (unsigned short*)alloc((size_t)N_ENT * 64 * 2);
  float* s_h    = (float*)alloc((size_t)N_ENT * 2 * 4);
  float* s_t    = (float*)alloc((size_t)N_ENT * 2 * 4);
  float* s_r    = (float*)alloc((size_t)N_REL * 2 * 4);
  float* cinv   = (float*)alloc((size_t)N_ENT * 2 * 4);
  float* csr_w  = (float*)alloc((size_t)N_EDGE * 2 * 4);
  unsigned short* Zb0 = (unsigned short*)alloc((size_t)N_ENT * 128 * 2);
  unsigned short* Zb1 = (unsigned short*)alloc((size_t)N_ENT * 128 * 2);
  int* deg      = (int*)alloc((size_t)N_ENT * 4);
  int* exc      = (int*)alloc((size_t)N_ENT * 4);
  int* bsum     = (int*)alloc((size_t)NBLK * 4);
  int* boff     = (int*)alloc((size_t)(NBLK + 1) * 4);
  int* rowptr   = (int*)alloc((size_t)(N_ENT + 1) * 4);
  int* cursor   = (int*)alloc((size_t)N_ENT * 4);
  int* csr_dst  = (int*)alloc((size_t)N_EDGE * 4);
  int* csr_et   = (int*)alloc((size_t)N_EDGE * 4);

  const int EB = (N_EDGE + 255) / 256;

  // ---- CSR build ----
  hipMemsetAsync(deg, 0, (size_t)N_ENT * 4, stream);
  deg_kernel<<<EB, 256, 0, stream>>>(src, deg);
  scan1_kernel<<<NBLK, 1024, 0, stream>>>(deg, exc, bsum);
  scan2_kernel<<<1, 64, 0, stream>>>(bsum, boff);
  scan3_kernel<<<NBLK, 1024, 0, stream>>>(exc, boff, rowptr);
  hipMemcpyAsync(cursor, rowptr, (size_t)N_ENT * 4, hipMemcpyDeviceToDevice, stream);
  scatter_kernel<<<EB, 256, 0, stream>>>(src, dst, et, cursor, csr_dst, csr_et);

  for (int l = 0; l < 2; ++l) {
    const float* x = (l == 0) ? ent0 : ent1;
    float* y = (l == 0) ? ent1 : outp;

    ln_kernel<<<(N_ENT + 3) / 4, 256, 0, stream>>>(x, gam + l * 64, bet + l * 64, h, h_bf);
    scores_w_kernel<<<1024, 256, 0, stream>>>(h, W_h + l * 8192, att_h + l * 128, s_h, N_ENT);
    scores_w_kernel<<<1024, 256, 0, stream>>>(h, W_t + l * 8192, att_t + l * 128, s_t, N_ENT);
    scores_w_kernel<<<8, 256, 0, stream>>>(rel, W_r + l * 8192, att_r + l * 128, s_r, N_REL);

    edge_csr_kernel<<<(N_ENT + 255) / 256, 256, 0, stream>>>(
        rowptr, csr_dst, csr_et, s_h, s_t, s_r, csr_w, cinv);

    // ---- PPR power iteration: h_bf -> Zb0 -> Zb1 -> Zb0 (all bf16) ----
    spmm_kernel<1><<<2048, 256, 0, stream>>>(rowptr, csr_dst, csr_w, cinv, h, h_bf, Zb0);
    spmm_kernel<0><<<2048, 256, 0, stream>>>(rowptr, csr_dst, csr_w, cinv, h, Zb0, Zb1);
    spmm_kernel<0><<<2048, 256, 0, stream>>>(rowptr, csr_dst, csr_w, cinv, h, Zb1, Zb0);

    out_kernel<<<1024, 256, 0, stream>>>(Zb0, W_o + l * 8192, x, y);
  }
}